// Round 7
// baseline (421.859 us; speedup 1.0000x reference)
//
#include <hip/hip_runtime.h>
#include <hip/hip_bf16.h>
#include <hip/hip_fp16.h>

// DeepSetPred: UNFUSED 3-GEMM pipeline (R7).
// L1: h1 = tanh(words @ W1 + b1)   [131072 x 256] x [256 x 512]  (words fp32, reg-staged)
// L2: h2 = tanh(h1 @ W2 + b2)      [131072 x 512] x [512 x 512]  (gload_lds staged)
// L3: enc += seg-sum(h2 @ W3 + b3) [131072 x 512] x [512 x 256]  (+fused segment sum)
// h1/h2 fp16 in workspace -> served by 256MB L3. m97 structure per GEMM:
// 128x128 tile, BK=64, 4 waves, dbuf LDS staging, 2-barrier K-loop,
// bias folded into acc init, XCD-aware swizzle (ft-fast for act locality).
// Fallback: if ws_size < NEED, run the R6 fused kernel (kept below).

typedef _Float16 half8v __attribute__((ext_vector_type(8)));
typedef _Float16 half4v __attribute__((ext_vector_type(4)));
typedef float f32x4 __attribute__((ext_vector_type(4)));

#define TANH_SCALE 2.8853900817779268f  // 2*log2(e)

__device__ __forceinline__ void gload_lds16(const void* g, void* l) {
    __builtin_amdgcn_global_load_lds(
        (const __attribute__((address_space(1))) void*)g,
        (__attribute__((address_space(3))) void*)l, 16, 0, 0);
}

// ---------------- weight transpose + fp16 cast (+tanh prescale, +bias scale) --
__global__ void wt_kernel(const float* __restrict__ W1, const float* __restrict__ W2,
                          const float* __restrict__ W3,
                          const float* __restrict__ b1, const float* __restrict__ b2,
                          _Float16* __restrict__ W1T, _Float16* __restrict__ W2T,
                          _Float16* __restrict__ W3T,
                          float* __restrict__ b1s, float* __restrict__ b2s) {
    int idx = blockIdx.x * 256 + threadIdx.x;
    if (idx < 512) b1s[idx] = b1[idx] * TANH_SCALE;
    else if (idx < 1024) b2s[idx - 512] = b2[idx - 512] * TANH_SCALE;
    if (idx < 131072) {                       // W1 [256][512] -> W1T [512][256], scaled
        int n = idx >> 8, k = idx & 255;
        W1T[idx] = (_Float16)(W1[k * 512 + n] * TANH_SCALE);
    } else if (idx < 393216) {                // W2 [512][512] -> W2T [512][512], scaled
        int j = idx - 131072, n = j >> 9, k = j & 511;
        W2T[j] = (_Float16)(W2[k * 512 + n] * TANH_SCALE);
    } else if (idx < 524288) {                // W3 [512][256] -> W3T [256][512]
        int j = idx - 393216, n = j >> 9, k = j & 511;
        W3T[j] = (_Float16)W3[k * 256 + n];
    }
}

// ---------------- unfused GEMM ----------------
// C[128 tok][128 feat] per block; D[feat][tok] via mfma(W-frag, act-frag).
// K: 256 or 512. AF32: act is fp32 (words), reg-staged w/ cvt. EPI: 0 tanh->fp16 h,
// 1 = f32 + segment-sum. FT: f-tiles in grid (M/128).
template<int K, bool AF32, int EPI, int FT>
__global__ __launch_bounds__(256, 2) void gemm_kernel(
    const void* __restrict__ act_, const _Float16* __restrict__ WT,
    const float* __restrict__ bias, void* __restrict__ out_,
    const int* __restrict__ seg_ids) {
    constexpr int NS = K / 64;
    constexpr int ASTR = AF32 ? 136 : 128;   // bytes per Abuf row (64 fp16 +pad if staged)
    constexpr int ASZ = 128 * ASTR;
    constexpr int AOFF = 32768;              // Wbuf: [0,32KB) two 16KB buffers
    constexpr int SMEM = (EPI == 1) ? (128 * 528 + 512) : (AOFF + 2 * ASZ);
    __shared__ __align__(16) char smem[SMEM];

    const int tid = threadIdx.x;
    const int lane = tid & 63;
    const int wave = tid >> 6;
    const int wm = wave >> 1, wn = wave & 1;   // 2x2 waves: 64 feats x 64 toks each

    // XCD-aware swizzle (grid % 8 == 0 always here); ft is the fast index so
    // consecutive logical blocks share the act tile.
    const int nwg = gridDim.x;
    const int wg = (blockIdx.x & 7) * (nwg >> 3) + (blockIdx.x >> 3);
    const int ft = wg % FT, tt = wg / FT;
    const long tok0 = (long)tt * 128;
    const int f0t = ft * 128;

    int* sseg = (int*)(smem + 128 * 528);    // EPI1 only (beyond 64KB stage area)
    if constexpr (EPI == 1) {
        if (tid < 128) sseg[tid] = seg_ids[tok0 + tid];
    }

    // bias -> acc init (D rows are feats: lane reg j = f0 + (lane>>4)*4 + j)
    const int fr0 = (lane >> 4) * 4;
    f32x4 acc[4][4];
    #pragma unroll
    for (int mt = 0; mt < 4; ++mt) {
        f32x4 bv = *(const f32x4*)(bias + f0t + wm * 64 + mt * 16 + fr0);
        #pragma unroll
        for (int nt = 0; nt < 4; ++nt) acc[mt][nt] = bv;
    }

    // ---- staging ----
    auto stage_w = [&](int s) {   // W tile [128 f][64 k] fp16, linear 128B rows
        const int k0 = s * 64, buf = s & 1;
        const _Float16* wsrc = WT + (size_t)f0t * K + k0;
        #pragma unroll
        for (int it = 0; it < 4; ++it) {
            int j = wave * 4 + it;                       // 16 instrs cover 128 rows
            const _Float16* gp = wsrc + (size_t)(j * 8 + (lane >> 3)) * K + (lane & 7) * 8;
            gload_lds16(gp, smem + buf * 16384 + j * 1024);
        }
    };
    auto stage_a = [&](int s) {   // act tile [128 t][64 k] fp16 via gload_lds
        const int k0 = s * 64, buf = s & 1;
        const _Float16* asrc = (const _Float16*)act_ + tok0 * K + k0;
        #pragma unroll
        for (int it = 0; it < 4; ++it) {
            int j = wave * 4 + it;
            const _Float16* gp = asrc + (size_t)(j * 8 + (lane >> 3)) * K + (lane & 7) * 8;
            gload_lds16(gp, smem + AOFF + buf * 16384 + j * 1024);
        }
    };
    // AF32 path: thread owns 32 floats of the [128 t][64 k] fp32 tile
    auto load_g = [&](int s, float4 g[8]) {
        const float* asrc = (const float*)act_ + tok0 * 256 + s * 64;
        const float4* p = (const float4*)(asrc + (size_t)(tid >> 1) * 256 + (tid & 1) * 32);
        #pragma unroll
        for (int c = 0; c < 8; ++c) g[c] = p[c];
    };
    auto write_g = [&](int s, const float4 g[8]) {
        char* dst = smem + AOFF + (s & 1) * ASZ + (tid >> 1) * 136 + (tid & 1) * 64;
        #pragma unroll
        for (int c = 0; c < 4; ++c) {
            half8v hv;
            hv[0] = (_Float16)g[2 * c].x;     hv[1] = (_Float16)g[2 * c].y;
            hv[2] = (_Float16)g[2 * c].z;     hv[3] = (_Float16)g[2 * c].w;
            hv[4] = (_Float16)g[2 * c + 1].x; hv[5] = (_Float16)g[2 * c + 1].y;
            hv[6] = (_Float16)g[2 * c + 1].z; hv[7] = (_Float16)g[2 * c + 1].w;
            *(half8v*)(dst + c * 16) = hv;
        }
    };

    auto compute = [&](int s) {
        const int buf = s & 1;
        const int r = lane & 15, g4 = lane >> 4;
        const char* wb = smem + buf * 16384 + (wm * 64 + r) * 128 + g4 * 16;
        const char* ab = smem + AOFF + buf * ASZ + (wn * 64 + r) * ASTR + g4 * 16;
        #pragma unroll
        for (int kk = 0; kk < 2; ++kk) {
            half8v a[4], b[4];
            #pragma unroll
            for (int mt = 0; mt < 4; ++mt)
                a[mt] = *(const half8v*)(wb + mt * 16 * 128 + kk * 64);
            #pragma unroll
            for (int nt = 0; nt < 4; ++nt)
                b[nt] = *(const half8v*)(ab + nt * 16 * ASTR + kk * 64);
            #pragma unroll
            for (int nt = 0; nt < 4; ++nt)
                #pragma unroll
                for (int mt = 0; mt < 4; ++mt)
                    acc[mt][nt] = __builtin_amdgcn_mfma_f32_16x16x32_f16(
                        a[mt], b[nt], acc[mt][nt], 0, 0, 0);
        }
    };

    // ---- K loop ----
    if constexpr (AF32) {                    // NS == 4, explicit static pipeline
        float4 gA[8], gB[8];
        stage_w(0); load_g(0, gA);
        stage_w(1); load_g(1, gB);
        write_g(0, gA); __syncthreads(); compute(0); __syncthreads();
        stage_w(2); load_g(2, gA);
        write_g(1, gB); __syncthreads(); compute(1); __syncthreads();
        stage_w(3); load_g(3, gB);
        write_g(2, gA); __syncthreads(); compute(2); __syncthreads();
        write_g(3, gB); __syncthreads(); compute(3); __syncthreads();
    } else {
        stage_w(0); stage_a(0);
        for (int s = 0; s < NS; ++s) {
            if (s + 1 < NS) { stage_w(s + 1); stage_a(s + 1); }
            __syncthreads();
            compute(s);
            __syncthreads();
        }
    }

    // ---- epilogue ----
    const int r = lane & 15;
    if constexpr (EPI == 0) {
        // tanh -> fp16 bounce [128 t][128 f] rows padded to 264B -> coalesced store
        constexpr int BR = 264;
        char* bo = smem;
        #pragma unroll
        for (int mt = 0; mt < 4; ++mt) {
            int fo = wm * 64 + mt * 16 + fr0;
            #pragma unroll
            for (int nt = 0; nt < 4; ++nt) {
                int t = wn * 64 + nt * 16 + r;
                half4v hv;
                #pragma unroll
                for (int j = 0; j < 4; ++j) {
                    float e = __builtin_amdgcn_exp2f(acc[mt][nt][j]);
                    float rr = __builtin_amdgcn_rcpf(e + 1.0f);
                    hv[j] = (_Float16)fmaf(-2.0f, rr, 1.0f);
                }
                *(half4v*)(bo + t * BR + fo * 2) = hv;
            }
        }
        __syncthreads();
        const int t = tid >> 1, seg = tid & 1;
        const uint4* src = (const uint4*)(bo + t * BR + seg * 128);
        _Float16* dst = (_Float16*)out_ + (tok0 + t) * 512 + f0t + seg * 64;
        #pragma unroll
        for (int c = 0; c < 8; ++c) ((uint4*)dst)[c] = src[c];
    } else {
        // f32 bounce [128 f][132 t floats] -> sorted-run segment sum -> atomics
        constexpr int BRF = 132;
        float* bo = (float*)smem;
        #pragma unroll
        for (int mt = 0; mt < 4; ++mt) {
            int fo = wm * 64 + mt * 16 + fr0;
            #pragma unroll
            for (int nt = 0; nt < 4; ++nt) {
                int t = wn * 64 + nt * 16 + r;
                #pragma unroll
                for (int j = 0; j < 4; ++j) bo[(fo + j) * BRF + t] = acc[mt][nt][j];
            }
        }
        __syncthreads();
        float* enc = (float*)out_;
        const int f = tid & 127, half = tid >> 7;
        const int t0 = half * 64;
        float a = 0.0f;
        int cur = sseg[t0];
        for (int i = 0; i < 64; ++i) {
            float v = bo[f * BRF + t0 + i];
            int s = sseg[t0 + i];
            if (s != cur) { atomicAdd(&enc[cur * 256 + f0t + f], a); a = 0.0f; cur = s; }
            a += v;
        }
        atomicAdd(&enc[cur * 256 + f0t + f], a);
    }
}

// ================= R6 fused fallback (used when ws_size is too small) =========
#define W_STR 528
#define H_STR 1040
#define E_STRF 65

template<int K, int STR>
__device__ __forceinline__ void mlp_pass(const _Float16* __restrict__ WT, int mbase,
                                         const char* lds_in, const float* sbias_layer,
                                         int lane, f32x4 acc[2][4]) {
    const int kgrp = 8 * (lane >> 4);
    const int r = lane & 15;
    const int fr0 = (lane >> 4) * 4;
    #pragma unroll
    for (int mt = 0; mt < 2; ++mt) {
        f32x4 bv = *(const f32x4*)(sbias_layer + mbase + mt * 16 + fr0);
        #pragma unroll
        for (int nt = 0; nt < 4; ++nt) acc[mt][nt] = bv;
    }
    const char* bbase = lds_in + r * STR + kgrp * 2;
    const _Float16* arow = WT + (size_t)(mbase + r) * K + kgrp;
    #pragma unroll
    for (int kk = 0; kk < K / 32; ++kk) {
        half8v a[2], b[4];
        #pragma unroll
        for (int mt = 0; mt < 2; ++mt)
            a[mt] = *(const half8v*)(arow + (size_t)mt * 16 * K + kk * 32);
        #pragma unroll
        for (int nt = 0; nt < 4; ++nt)
            b[nt] = *(const half8v*)(bbase + nt * 16 * STR + kk * 64);
        #pragma unroll
        for (int nt = 0; nt < 4; ++nt)
            #pragma unroll
            for (int mt = 0; mt < 2; ++mt)
                acc[mt][nt] = __builtin_amdgcn_mfma_f32_16x16x32_f16(
                    a[mt], b[nt], acc[mt][nt], 0, 0, 0);
    }
}

__device__ __forceinline__ void store_h2(char* lds_out, const f32x4 acc[2][4],
                                         int mbase, int lane) {
    const int r = lane & 15;
    const int fr0 = (lane >> 4) * 4;
    #pragma unroll
    for (int mt = 0; mt < 2; ++mt) {
        int f0 = mbase + mt * 16 + fr0;
        #pragma unroll
        for (int nt = 0; nt < 4; ++nt) {
            int t = nt * 16 + r;
            half4v hv;
            #pragma unroll
            for (int reg = 0; reg < 4; ++reg) {
                float e = __builtin_amdgcn_exp2f(acc[mt][nt][reg]);
                float rr = __builtin_amdgcn_rcpf(e + 1.0f);
                hv[reg] = (_Float16)fmaf(-2.0f, rr, 1.0f);
            }
            *(half4v*)(lds_out + t * H_STR + f0 * 2) = hv;
        }
    }
}

__global__ __launch_bounds__(512, 4) void encoder_fused(
    const float* __restrict__ words, const int* __restrict__ seg_ids,
    const _Float16* __restrict__ W1T, const _Float16* __restrict__ W2T,
    const _Float16* __restrict__ W3T,
    const float* __restrict__ b1, const float* __restrict__ b2,
    const float* __restrict__ b3, float* __restrict__ enc) {
    __shared__ __align__(16) char buf[66560];
    __shared__ __align__(16) float sbias[1280];
    __shared__ int sseg[64];
    const int tid = threadIdx.x;
    const int lane = tid & 63;
    const int wave = tid >> 6;
    const int tok0 = blockIdx.x * 64;
    sbias[tid] = b1[tid] * TANH_SCALE;
    sbias[512 + tid] = b2[tid] * TANH_SCALE;
    if (tid < 256) sbias[1024 + tid] = b3[tid];
    if (tid < 64) sseg[tid] = seg_ids[tok0 + tid];
    const float* wsrc = words + (size_t)tok0 * 256;
    #pragma unroll
    for (int it = 0; it < 8; ++it) {
        int i = it * 512 + tid;
        float4 v = ((const float4*)wsrc)[i];
        int t = i >> 6, col = i & 63;
        half4v hv = { (_Float16)v.x, (_Float16)v.y, (_Float16)v.z, (_Float16)v.w };
        *(half4v*)(buf + t * W_STR + col * 8) = hv;
    }
    __syncthreads();
    {
        f32x4 accA[2][4], accB[2][4];
        mlp_pass<256, W_STR>(W1T, wave * 32, buf, sbias, lane, accA);
        mlp_pass<256, W_STR>(W1T, wave * 32 + 256, buf, sbias, lane, accB);
        __syncthreads();
        store_h2(buf, accA, wave * 32, lane);
        store_h2(buf, accB, wave * 32 + 256, lane);
    }
    __syncthreads();
    {
        f32x4 accA[2][4], accB[2][4];
        mlp_pass<512, H_STR>(W2T, wave * 32, buf, sbias + 512, lane, accA);
        mlp_pass<512, H_STR>(W2T, wave * 32 + 256, buf, sbias + 512, lane, accB);
        __syncthreads();
        store_h2(buf, accA, wave * 32, lane);
        store_h2(buf, accB, wave * 32 + 256, lane);
    }
    __syncthreads();
    {
        f32x4 acc[2][4];
        mlp_pass<512, H_STR>(W3T, wave * 32, buf, sbias + 1024, lane, acc);
        __syncthreads();
        float* encT = (float*)buf;
        const int r = lane & 15;
        const int fr0 = (lane >> 4) * 4;
        #pragma unroll
        for (int mt = 0; mt < 2; ++mt) {
            int f0 = wave * 32 + mt * 16 + fr0;
            #pragma unroll
            for (int nt = 0; nt < 4; ++nt) {
                int t = nt * 16 + r;
                #pragma unroll
                for (int reg = 0; reg < 4; ++reg)
                    encT[(f0 + reg) * E_STRF + t] = acc[mt][nt][reg];
            }
        }
    }
    __syncthreads();
    {
        int f = tid & 255, hh = tid >> 8, t0 = hh * 32;
        const float* encT = (const float*)buf;
        float a = 0.0f;
        int cur = sseg[t0];
        for (int i = 0; i < 32; ++i) {
            int t = t0 + i;
            float v = encT[f * E_STRF + t];
            int s = sseg[t];
            if (s != cur) { atomicAdd(&enc[cur * 256 + f], a); a = 0.0f; cur = s; }
            a += v;
        }
        atomicAdd(&enc[cur * 256 + f], a);
    }
}

// ---------------- predictor (tiny, fp32) ----------------
__global__ __launch_bounds__(256) void pred_kernel(
    const float* __restrict__ enc,
    const float* __restrict__ P1, const float* __restrict__ pb1,
    const float* __restrict__ P2, const float* __restrict__ pb2,
    const float* __restrict__ P3, const float* __restrict__ pb3,
    float* __restrict__ out) {
    __shared__ float se[256];
    __shared__ float sp[512];
    __shared__ float red[256];
    const int tid = threadIdx.x, b = blockIdx.x;
    se[tid] = enc[b * 256 + tid];
    __syncthreads();
    float a0 = pb1[tid], a1 = pb1[tid + 256];
    for (int k = 0; k < 256; ++k) {
        float e = se[k];
        a0 = fmaf(e, P1[k * 512 + tid], a0);
        a1 = fmaf(e, P1[k * 512 + tid + 256], a1);
    }
    sp[tid] = tanhf(a0);
    sp[tid + 256] = tanhf(a1);
    __syncthreads();
    a0 = pb2[tid]; a1 = pb2[tid + 256];
    for (int k = 0; k < 512; ++k) {
        float p = sp[k];
        a0 = fmaf(p, P2[k * 512 + tid], a0);
        a1 = fmaf(p, P2[k * 512 + tid + 256], a1);
    }
    __syncthreads();
    sp[tid] = tanhf(a0);
    sp[tid + 256] = tanhf(a1);
    __syncthreads();
    int j = tid & 31, part = tid >> 5;
    float s = 0.0f;
    for (int k = part * 64; k < part * 64 + 64; ++k)
        s = fmaf(sp[k], P3[k * 32 + j], s);
    red[tid] = s;
    __syncthreads();
    if (tid < 128) red[tid] += red[tid + 128];
    __syncthreads();
    if (tid < 64) red[tid] += red[tid + 64];
    __syncthreads();
    if (tid < 32) out[b * 32 + tid] = red[tid] + red[tid + 32] + pb3[tid];
}

extern "C" void kernel_launch(void* const* d_in, const int* in_sizes, int n_in,
                              void* d_out, int out_size, void* d_ws, size_t ws_size,
                              hipStream_t stream) {
    const float* words = (const float*)d_in[0];
    const int* seg_ids = (const int*)d_in[1];
    const float* W1 = (const float*)d_in[2];
    const float* b1 = (const float*)d_in[3];
    const float* W2 = (const float*)d_in[4];
    const float* b2 = (const float*)d_in[5];
    const float* W3 = (const float*)d_in[6];
    const float* b3 = (const float*)d_in[7];
    const float* P1 = (const float*)d_in[8];
    const float* pb1 = (const float*)d_in[9];
    const float* P2 = (const float*)d_in[10];
    const float* pb2 = (const float*)d_in[11];
    const float* P3 = (const float*)d_in[12];
    const float* pb3 = (const float*)d_in[13];
    float* out = (float*)d_out;

    char* ws = (char*)d_ws;
    _Float16* W1T = (_Float16*)(ws);                 // 262144 B
    _Float16* W2T = (_Float16*)(ws + 262144);        // 524288 B
    _Float16* W3T = (_Float16*)(ws + 786432);        // 262144 B
    float* b1s = (float*)(ws + 1048576);             // 2048 B
    float* b2s = (float*)(ws + 1050624);             // 2048 B
    float* enc = (float*)(ws + 1052672);             // 131072 B
    _Float16* h1 = (_Float16*)(ws + 1183744);        // 134217728 B
    _Float16* h2 = (_Float16*)(ws + 135401472);      // 134217728 B
    const size_t NEED = 269619200;

    hipMemsetAsync(enc, 0, 128 * 256 * 4, stream);
    wt_kernel<<<2048, 256, 0, stream>>>(W1, W2, W3, b1, b2, W1T, W2T, W3T, b1s, b2s);

    if (ws_size >= NEED) {
        gemm_kernel<256, true, 0, 4><<<4096, 256, 0, stream>>>(
            (const void*)words, W1T, b1s, (void*)h1, nullptr);
        gemm_kernel<512, false, 0, 4><<<4096, 256, 0, stream>>>(
            (const void*)h1, W2T, b2s, (void*)h2, nullptr);
        gemm_kernel<512, false, 1, 2><<<2048, 256, 0, stream>>>(
            (const void*)h2, W3T, b3, (void*)enc, seg_ids);
    } else {
        encoder_fused<<<2048, 512, 0, stream>>>(words, seg_ids, W1T, W2T, W3T,
                                                b1, b2, b3, enc);
    }
    pred_kernel<<<128, 256, 0, stream>>>(enc, P1, pb1, P2, pb2, P3, pb3, out);
}

// Round 8
// 312.172 us; speedup vs baseline: 1.3514x; 1.3514x over previous
//
#include <hip/hip_runtime.h>
#include <hip/hip_bf16.h>
#include <hip/hip_fp16.h>

// DeepSetPred: encoder MLP (MFMA fp16) -> segment sum -> predictor MLP (fp32)
// T=131072, E=256, H=512, C=256, O=32, NSEG=128
// R8: fused kernel rebuilt on mfma_f32_32x32x16_f16 (2x FLOP per operand byte
//     vs 16x16x32). Per K-step(16): 2 A global loads + 2 B LDS frags -> 4 MFMA
//     (129 SIMD-cy cover). Register budget finally admits a depth-2 A ring
//     (258cy lead >= L2 latency) + depth-1 B ring: acc 64 + A 24 + B 16 +
//     bases ~10 = ~115 < 128 cap at 4 waves/SIMD. All loop offsets are
//     compile-time immediates (zero in-loop address VALU). Act stride 1032B:
//     b64-pair reads, bank step 2 -> 2-way aliasing = free (m136).

typedef _Float16 half8v __attribute__((ext_vector_type(8)));
typedef _Float16 half4v __attribute__((ext_vector_type(4)));
typedef float f32x4 __attribute__((ext_vector_type(4)));
typedef float f32x16 __attribute__((ext_vector_type(16)));

#define TANH_SCALE 2.8853900817779268f  // 2*log2(e)
#define A_STR 1032                      // act row stride (bytes): 2-way-free, b64-aligned
#define E_STRF 65                       // encT row stride (floats)

// ---------------- weight transpose + fp16 cast (+tanh prescale) --------------
__global__ void wt_kernel(const float* __restrict__ W1, const float* __restrict__ W2,
                          const float* __restrict__ W3,
                          _Float16* __restrict__ W1T, _Float16* __restrict__ W2T,
                          _Float16* __restrict__ W3T) {
    int idx = blockIdx.x * 256 + threadIdx.x;
    if (idx < 131072) {                       // W1 [256][512] -> W1T [512][256], scaled
        int n = idx >> 8, k = idx & 255;
        W1T[idx] = (_Float16)(W1[k * 512 + n] * TANH_SCALE);
    } else if (idx < 393216) {                // W2 [512][512] -> W2T [512][512], scaled
        int j = idx - 131072, n = j >> 9, k = j & 511;
        W2T[j] = (_Float16)(W2[k * 512 + n] * TANH_SCALE);
    } else if (idx < 524288) {                // W3 [512][256] -> W3T [256][512]
        int j = idx - 393216, n = j >> 9, k = j & 511;
        W3T[j] = (_Float16)W3[k * 256 + n];
    }
}

// B fragment: act[t=lane&31][k-chunk] as two b64 reads (conflict-free at A_STR)
__device__ __forceinline__ half8v read_b(const char* p, int off) {
    uint2 lo = *(const uint2*)(p + off);
    uint2 hi = *(const uint2*)(p + off + 8);
    uint4 w;
    w.x = lo.x; w.y = lo.y; w.z = hi.x; w.w = hi.y;
    return __builtin_bit_cast(half8v, w);
}

// ---------------- encoder pass: D[f][t] = WT(MT*32 x K) * actT(K x 64) -------
// 32x32x16 MFMA. A: lane row=l&31, k-chunk 8*(l>>5). B: lane col(token)=l&31.
// K-loop: depth-2 A prefetch ring, depth-1 B ring, fully unrolled.
template<int K, int MT>
__device__ __forceinline__ void mlp_pass32(const _Float16* __restrict__ WT,
                                           int fbase, const char* lds_act,
                                           const float* sbias_layer, int lane,
                                           f32x16 acc[MT][2]) {
    const int r2 = lane & 31;
    const int hi = lane >> 5;
    // bias -> acc init: D row = (reg&3) + 8*(reg>>2) + 4*hi
    #pragma unroll
    for (int mt = 0; mt < MT; ++mt)
        #pragma unroll
        for (int q = 0; q < 4; ++q) {
            f32x4 bv = *(const f32x4*)(sbias_layer + fbase + mt * 32 + hi * 4 + q * 8);
            #pragma unroll
            for (int j = 0; j < 4; ++j) {
                acc[mt][0][q * 4 + j] = bv[j];
                acc[mt][1][q * 4 + j] = bv[j];
            }
        }
    const _Float16* ab[MT];
    ab[0] = WT + (size_t)(fbase + r2) * K + hi * 8;
    if constexpr (MT == 2) ab[1] = ab[0] + (size_t)32 * K;
    const char* bb = lds_act + r2 * A_STR + hi * 16;

    constexpr int NS = K / 16;
    half8v A[3][MT], B[2][2];
    #pragma unroll
    for (int mt = 0; mt < MT; ++mt) {
        A[0][mt] = *(const half8v*)(ab[mt]);
        A[1][mt] = *(const half8v*)(ab[mt] + 16);
    }
    #pragma unroll
    for (int nt = 0; nt < 2; ++nt)
        B[0][nt] = read_b(bb, nt * 32 * A_STR);

    #pragma unroll
    for (int s = 0; s < NS; ++s) {
        if (s + 2 < NS) {
            #pragma unroll
            for (int mt = 0; mt < MT; ++mt)
                A[(s + 2) % 3][mt] = *(const half8v*)(ab[mt] + (s + 2) * 16);
        }
        if (s + 1 < NS) {
            #pragma unroll
            for (int nt = 0; nt < 2; ++nt)
                B[(s + 1) & 1][nt] = read_b(bb, nt * 32 * A_STR + (s + 1) * 32);
        }
        #pragma unroll
        for (int nt = 0; nt < 2; ++nt)
            #pragma unroll
            for (int mt = 0; mt < MT; ++mt)
                acc[mt][nt] = __builtin_amdgcn_mfma_f32_32x32x16_f16(
                    A[s % 3][mt], B[s & 1][nt], acc[mt][nt], 0, 0, 0);
    }
}

// acc (bias folded, pre-scaled by 2*log2e) -> tanh -> fp16 LDS [t][f]
template<int MT>
__device__ __forceinline__ void store_h32(char* lds_out, const f32x16 acc[MT][2],
                                          int fbase, int lane) {
    const int t_lo = lane & 31;
    const int hi = lane >> 5;
    #pragma unroll
    for (int mt = 0; mt < MT; ++mt)
        #pragma unroll
        for (int nt = 0; nt < 2; ++nt) {
            int t = nt * 32 + t_lo;
            #pragma unroll
            for (int q = 0; q < 4; ++q) {
                int f0 = fbase + mt * 32 + hi * 4 + q * 8;
                half4v hv;
                #pragma unroll
                for (int j = 0; j < 4; ++j) {
                    float e = __builtin_amdgcn_exp2f(acc[mt][nt][q * 4 + j]);
                    float rr = __builtin_amdgcn_rcpf(e + 1.0f);
                    hv[j] = (_Float16)fmaf(-2.0f, rr, 1.0f);
                }
                *(half4v*)(lds_out + t * A_STR + f0 * 2) = hv;
            }
        }
}

__global__ __launch_bounds__(512, 4) void encoder_kernel(
    const float* __restrict__ words, const int* __restrict__ seg_ids,
    const _Float16* __restrict__ W1T, const _Float16* __restrict__ W2T,
    const _Float16* __restrict__ W3T,
    const float* __restrict__ b1, const float* __restrict__ b2,
    const float* __restrict__ b3, float* __restrict__ enc) {
    __shared__ __align__(16) char buf[66560];   // act 64x1032 / encT 256x65x4
    __shared__ __align__(16) float sbias[1280]; // s*b1(512) s*b2(512) b3(256)
    __shared__ int sseg[64];

    const int tid = threadIdx.x;
    const int lane = tid & 63;
    const int wave = tid >> 6;
    const int tok0 = blockIdx.x * 64;

    sbias[tid] = b1[tid] * TANH_SCALE;
    sbias[512 + tid] = b2[tid] * TANH_SCALE;
    if (tid < 256) sbias[1024 + tid] = b3[tid];
    if (tid < 64) sseg[tid] = seg_ids[tok0 + tid];

    // stage words tile -> fp16 LDS [t][k], row stride 1032B
    const float* wsrc = words + (size_t)tok0 * 256;
    #pragma unroll
    for (int it = 0; it < 8; ++it) {
        int i = it * 512 + tid;            // float4 index, 4096 total
        float4 v = ((const float4*)wsrc)[i];
        int t = i >> 6;
        int col = i & 63;                  // 8B half4 slot within row
        half4v hv = { (_Float16)v.x, (_Float16)v.y, (_Float16)v.z, (_Float16)v.w };
        *(half4v*)(buf + t * A_STR + col * 8) = hv;
    }
    __syncthreads();

    // layer 1: words[64][256] -> h1[64][512] (in place)
    {
        f32x16 acc[2][2];
        mlp_pass32<256, 2>(W1T, wave * 64, buf, sbias, lane, acc);
        __syncthreads();
        store_h32<2>(buf, acc, wave * 64, lane);
    }
    __syncthreads();

    // layer 2: h1 -> h2 (in place)
    {
        f32x16 acc[2][2];
        mlp_pass32<512, 2>(W2T, wave * 64, buf, sbias + 512, lane, acc);
        __syncthreads();
        store_h32<2>(buf, acc, wave * 64, lane);
    }
    __syncthreads();

    // layer 3: h2 -> encT [256][65] f32 (in place; bias folded, no tanh)
    {
        f32x16 acc[1][2];
        mlp_pass32<512, 1>(W3T, wave * 32, buf, sbias + 1024, lane, acc);
        __syncthreads();
        float* encT = (float*)buf;
        const int t_lo = lane & 31;
        const int hi = lane >> 5;
        #pragma unroll
        for (int nt = 0; nt < 2; ++nt) {
            int t = nt * 32 + t_lo;
            #pragma unroll
            for (int q = 0; q < 4; ++q) {
                int f0 = wave * 32 + hi * 4 + q * 8;
                #pragma unroll
                for (int j = 0; j < 4; ++j)
                    encT[(f0 + j) * E_STRF + t] = acc[0][nt][q * 4 + j];
            }
        }
    }
    __syncthreads();

    // segment reduction: sorted seg_ids -> running sum, atomic on boundary
    {
        int f = tid & 255;
        int hh = tid >> 8;
        int t0 = hh * 32;
        const float* encT = (const float*)buf;
        float a = 0.0f;
        int cur = sseg[t0];
        for (int i = 0; i < 32; ++i) {
            int t = t0 + i;
            float v = encT[f * E_STRF + t];
            int s = sseg[t];
            if (s != cur) { atomicAdd(&enc[cur * 256 + f], a); a = 0.0f; cur = s; }
            a += v;
        }
        atomicAdd(&enc[cur * 256 + f], a);
    }
}

// ---------------- predictor (tiny, fp32) ----------------
__global__ __launch_bounds__(256) void pred_kernel(
    const float* __restrict__ enc,
    const float* __restrict__ P1, const float* __restrict__ pb1,
    const float* __restrict__ P2, const float* __restrict__ pb2,
    const float* __restrict__ P3, const float* __restrict__ pb3,
    float* __restrict__ out) {
    __shared__ float se[256];
    __shared__ float sp[512];
    __shared__ float red[256];
    const int tid = threadIdx.x, b = blockIdx.x;
    se[tid] = enc[b * 256 + tid];
    __syncthreads();
    float a0 = pb1[tid], a1 = pb1[tid + 256];
    for (int k = 0; k < 256; ++k) {
        float e = se[k];
        a0 = fmaf(e, P1[k * 512 + tid], a0);
        a1 = fmaf(e, P1[k * 512 + tid + 256], a1);
    }
    sp[tid] = tanhf(a0);
    sp[tid + 256] = tanhf(a1);
    __syncthreads();
    a0 = pb2[tid]; a1 = pb2[tid + 256];
    for (int k = 0; k < 512; ++k) {
        float p = sp[k];
        a0 = fmaf(p, P2[k * 512 + tid], a0);
        a1 = fmaf(p, P2[k * 512 + tid + 256], a1);
    }
    __syncthreads();
    sp[tid] = tanhf(a0);
    sp[tid + 256] = tanhf(a1);
    __syncthreads();
    int j = tid & 31, part = tid >> 5;
    float s = 0.0f;
    for (int k = part * 64; k < part * 64 + 64; ++k)
        s = fmaf(sp[k], P3[k * 32 + j], s);
    red[tid] = s;
    __syncthreads();
    if (tid < 128) red[tid] += red[tid + 128];
    __syncthreads();
    if (tid < 64) red[tid] += red[tid + 64];
    __syncthreads();
    if (tid < 32) out[b * 32 + tid] = red[tid] + red[tid + 32] + pb3[tid];
}

extern "C" void kernel_launch(void* const* d_in, const int* in_sizes, int n_in,
                              void* d_out, int out_size, void* d_ws, size_t ws_size,
                              hipStream_t stream) {
    const float* words = (const float*)d_in[0];
    const int* seg_ids = (const int*)d_in[1];
    const float* W1 = (const float*)d_in[2];
    const float* b1 = (const float*)d_in[3];
    const float* W2 = (const float*)d_in[4];
    const float* b2 = (const float*)d_in[5];
    const float* W3 = (const float*)d_in[6];
    const float* b3 = (const float*)d_in[7];
    const float* P1 = (const float*)d_in[8];
    const float* pb1 = (const float*)d_in[9];
    const float* P2 = (const float*)d_in[10];
    const float* pb2 = (const float*)d_in[11];
    const float* P3 = (const float*)d_in[12];
    const float* pb3 = (const float*)d_in[13];
    float* out = (float*)d_out;

    char* ws = (char*)d_ws;
    _Float16* W1T = (_Float16*)(ws);            // 512*256*2 = 256KB
    _Float16* W2T = (_Float16*)(ws + 262144);   // 512*512*2 = 512KB
    _Float16* W3T = (_Float16*)(ws + 786432);   // 256*512*2 = 256KB
    float* enc = (float*)(ws + 1048576);        // 128*256*4 = 128KB

    hipMemsetAsync(enc, 0, 128 * 256 * 4, stream);
    wt_kernel<<<524288 / 256, 256, 0, stream>>>(W1, W2, W3, W1T, W2T, W3T);
    encoder_kernel<<<2048, 512, 0, stream>>>(words, seg_ids, W1T, W2T, W3T,
                                             b1, b2, b3, enc);
    pred_kernel<<<128, 256, 0, stream>>>(enc, P1, pb1, P2, pb2, P3, pb3, out);
}

// Round 9
// 305.030 us; speedup vs baseline: 1.3830x; 1.0234x over previous
//
#include <hip/hip_runtime.h>
#include <hip/hip_bf16.h>
#include <hip/hip_fp16.h>

// DeepSetPred: encoder MLP (MFMA fp16) -> segment sum -> predictor MLP (fp32)
// T=131072, E=256, H=512, C=256, O=32, NSEG=128
// R9: BOTH MFMA operands from LDS. Weights stream through dbuf LDS tiles
//     [256f][64k] staged via global_load_lds16, COALESCED (8 lanes per 128B row)
//     with XOR source-pre-swizzle (slot ^= row&7); A ds_read_b128 applies the
//     same XOR -> 4-way residual (1.58x). Acts in 1032B-stride rows (0-conflict,
//     measured). 2 feature passes x 256f (acc 32+32 AGPR) keep in-place store
//     legal. m97 2-barrier K-step; cross-layer W prefetch. 134KB LDS, 1 blk/CU.
//     R8 post-mortem: per-lane weight gather = 32 scattered sectors/instr was
//     the invariant transaction-rate wall across R1-R8 (~305us, MfmaUtil 19%).

typedef _Float16 half8v __attribute__((ext_vector_type(8)));
typedef _Float16 half4v __attribute__((ext_vector_type(4)));
typedef float f32x4 __attribute__((ext_vector_type(4)));
typedef float f32x16 __attribute__((ext_vector_type(16)));

#define TANH_SCALE 2.8853900817779268f  // 2*log2(e)
#define A_STR 1032                      // act row stride bytes (2-way-free, b64)
#define E_STRF 65                       // encT row stride (floats)
#define WTILE 32768                     // one W buffer: 256 rows x 128B

__device__ __forceinline__ void gload_lds16(const void* g, void* l) {
    __builtin_amdgcn_global_load_lds(
        (const __attribute__((address_space(1))) void*)g,
        (__attribute__((address_space(3))) void*)l, 16, 0, 0);
}

// ---------------- weight transpose + fp16 cast (+tanh prescale) --------------
__global__ void wt_kernel(const float* __restrict__ W1, const float* __restrict__ W2,
                          const float* __restrict__ W3,
                          _Float16* __restrict__ W1T, _Float16* __restrict__ W2T,
                          _Float16* __restrict__ W3T) {
    int idx = blockIdx.x * 256 + threadIdx.x;
    if (idx < 131072) {                       // W1 [256][512] -> W1T [512][256], scaled
        int n = idx >> 8, k = idx & 255;
        W1T[idx] = (_Float16)(W1[k * 512 + n] * TANH_SCALE);
    } else if (idx < 393216) {                // W2 [512][512] -> W2T [512][512], scaled
        int j = idx - 131072, n = j >> 9, k = j & 511;
        W2T[j] = (_Float16)(W2[k * 512 + n] * TANH_SCALE);
    } else if (idx < 524288) {                // W3 [512][256] -> W3T [256][512]
        int j = idx - 393216, n = j >> 9, k = j & 511;
        W3T[j] = (_Float16)W3[k * 256 + n];
    }
}

// B fragment from act LDS: two b64 reads (conflict-free at A_STR)
__device__ __forceinline__ half8v read_b(const char* p, int off) {
    uint2 lo = *(const uint2*)(p + off);
    uint2 hi = *(const uint2*)(p + off + 8);
    uint4 w;
    w.x = lo.x; w.y = lo.y; w.z = hi.x; w.w = hi.y;
    return __builtin_bit_cast(half8v, w);
}

__global__ __launch_bounds__(512, 2) void encoder_kernel(
    const float* __restrict__ words, const int* __restrict__ seg_ids,
    const _Float16* __restrict__ W1T, const _Float16* __restrict__ W2T,
    const _Float16* __restrict__ W3T,
    const float* __restrict__ b1, const float* __restrict__ b2,
    const float* __restrict__ b3, float* __restrict__ enc) {
    __shared__ __align__(16) char wbuf[2 * WTILE];  // 64KB: dbuf W tiles [256][128B]
    __shared__ __align__(16) char act[66048];       // 64 x 1032B
    __shared__ __align__(16) float sbias[1280];     // s*b1(512) s*b2(512) b3(256)
    __shared__ int sseg[64];

    const int tid = threadIdx.x;
    const int lane = tid & 63;
    const int wave = tid >> 6;
    const int tok0 = blockIdx.x * 64;

    const int r2 = lane & 31;
    const int hi = lane >> 5;
    const int r7 = (r2 & 7) << 4;

    // ---- staging helpers ----
    // W tile: LDS slot (row, lslot) <- global k-slot (lslot ^ (row&7)).
    auto stage_w = [&](int buf, const _Float16* Wsrc, int k0, int K) {
        char* dst = wbuf + buf * WTILE;
        #pragma unroll
        for (int it = 0; it < 4; ++it) {
            int c = wave * 4 + it;                       // 1KB chunk = 8 rows
            int row = c * 8 + (lane >> 3);
            int gslot = (lane & 7) ^ (row & 7);
            const _Float16* gp = Wsrc + (size_t)row * K + k0 + gslot * 8;
            gload_lds16(gp, dst + c * 1024);
        }
    };

    auto init_bias = [&](f32x16 acc[2], const float* base) {
        #pragma unroll
        for (int q = 0; q < 4; ++q) {
            f32x4 bv = *(const f32x4*)(base + hi * 4 + q * 8);
            #pragma unroll
            for (int j = 0; j < 4; ++j) {
                acc[0][q * 4 + j] = bv[j];
                acc[1][q * 4 + j] = bv[j];
            }
        }
    };

    const char* actb_base = act + r2 * A_STR + hi * 16;
    // one K-step (64 k): 4 x (A b128 + 2 B reads + 2 MFMA)
    auto compute = [&](f32x16 acc[2], int buf, int kstep) {
        const char* wrow = wbuf + buf * WTILE + (wave * 32 + r2) * 128;
        const char* actb = actb_base + kstep * 128;
        #pragma unroll
        for (int s = 0; s < 4; ++s) {
            half8v A = *(const half8v*)(wrow + ((((s * 2 + hi) << 4)) ^ r7));
            half8v B0 = read_b(actb, s * 32);
            half8v B1 = read_b(actb, 32 * A_STR + s * 32);
            acc[0] = __builtin_amdgcn_mfma_f32_32x32x16_f16(A, B0, acc[0], 0, 0, 0);
            acc[1] = __builtin_amdgcn_mfma_f32_32x32x16_f16(A, B1, acc[1], 0, 0, 0);
        }
    };

    // tanh -> fp16, in-place into act [t][f]
    auto store_h = [&](const f32x16 acc[2], int fbase) {
        #pragma unroll
        for (int nt = 0; nt < 2; ++nt) {
            int t = nt * 32 + r2;
            #pragma unroll
            for (int q = 0; q < 4; ++q) {
                int f0 = fbase + hi * 4 + q * 8;
                half4v hv;
                #pragma unroll
                for (int j = 0; j < 4; ++j) {
                    float e = __builtin_amdgcn_exp2f(acc[nt][q * 4 + j]);
                    float rr = __builtin_amdgcn_rcpf(e + 1.0f);
                    hv[j] = (_Float16)fmaf(-2.0f, rr, 1.0f);
                }
                *(half4v*)(act + t * A_STR + f0 * 2) = hv;
            }
        }
    };

    // ---- prologue ----
    sbias[tid] = b1[tid] * TANH_SCALE;
    sbias[512 + tid] = b2[tid] * TANH_SCALE;
    if (tid < 256) sbias[1024 + tid] = b3[tid];
    if (tid < 64) sseg[tid] = seg_ids[tok0 + tid];

    {   // stage words tile -> fp16 act rows (coalesced fp32 reads)
        const float* wsrc = words + (size_t)tok0 * 256;
        #pragma unroll
        for (int it = 0; it < 8; ++it) {
            int i = it * 512 + tid;
            float4 v = ((const float4*)wsrc)[i];
            int t = i >> 6;
            int col = i & 63;
            half4v hv = { (_Float16)v.x, (_Float16)v.y, (_Float16)v.z, (_Float16)v.w };
            *(half4v*)(act + t * A_STR + col * 8) = hv;
        }
    }
    stage_w(0, W1T, 0, 256);
    __syncthreads();

    int buf = 0;
    f32x16 accA[2], accB[2];

    // ================= layer 1: K=256, out 512 (2 passes) =================
    init_bias(accA, sbias + wave * 32);
    init_bias(accB, sbias + 256 + wave * 32);
    #pragma unroll
    for (int s = 0; s < 4; ++s) {           // pass 0
        if (s < 3) stage_w(buf ^ 1, W1T, (s + 1) * 64, 256);
        else       stage_w(buf ^ 1, W1T + 256 * 256, 0, 256);
        compute(accA, buf, s);
        buf ^= 1;
        __syncthreads();
    }
    #pragma unroll
    for (int s = 0; s < 4; ++s) {           // pass 1
        if (s < 3) stage_w(buf ^ 1, W1T + 256 * 256, (s + 1) * 64, 256);
        else       stage_w(buf ^ 1, W2T, 0, 512);   // prefetch L2 tile 0
        compute(accB, buf, s);
        buf ^= 1;
        __syncthreads();
    }
    store_h(accA, wave * 32);
    store_h(accB, 256 + wave * 32);
    __syncthreads();

    // ================= layer 2: K=512, out 512 (2 passes) =================
    init_bias(accA, sbias + 512 + wave * 32);
    init_bias(accB, sbias + 768 + wave * 32);
    #pragma unroll
    for (int s = 0; s < 8; ++s) {           // pass 0
        if (s < 7) stage_w(buf ^ 1, W2T, (s + 1) * 64, 512);
        else       stage_w(buf ^ 1, W2T + 256 * 512, 0, 512);
        compute(accA, buf, s);
        buf ^= 1;
        __syncthreads();
    }
    #pragma unroll
    for (int s = 0; s < 8; ++s) {           // pass 1
        if (s < 7) stage_w(buf ^ 1, W2T + 256 * 512, (s + 1) * 64, 512);
        else       stage_w(buf ^ 1, W3T, 0, 512);   // prefetch L3 tile 0
        compute(accB, buf, s);
        buf ^= 1;
        __syncthreads();
    }
    store_h(accA, wave * 32);
    store_h(accB, 256 + wave * 32);
    __syncthreads();

    // ================= layer 3: K=512, out 256 (1 pass, f32, no tanh) =====
    init_bias(accA, sbias + 1024 + wave * 32);
    #pragma unroll
    for (int s = 0; s < 8; ++s) {
        if (s < 7) stage_w(buf ^ 1, W3T, (s + 1) * 64, 512);
        compute(accA, buf, s);
        buf ^= 1;
        __syncthreads();
    }
    {   // encT [256 f][65 floats] into act buffer (reads done)
        float* encT = (float*)act;
        #pragma unroll
        for (int nt = 0; nt < 2; ++nt) {
            int t = nt * 32 + r2;
            #pragma unroll
            for (int q = 0; q < 4; ++q) {
                int f0 = wave * 32 + hi * 4 + q * 8;
                #pragma unroll
                for (int j = 0; j < 4; ++j)
                    encT[(f0 + j) * E_STRF + t] = accA[nt][q * 4 + j];
            }
        }
    }
    __syncthreads();

    // segment reduction: sorted seg_ids -> running sum, atomic on boundary
    {
        int f = tid & 255;
        int hh = tid >> 8;
        int t0 = hh * 32;
        const float* encT = (const float*)act;
        float a = 0.0f;
        int cur = sseg[t0];
        for (int i = 0; i < 32; ++i) {
            int t = t0 + i;
            float v = encT[f * E_STRF + t];
            int s = sseg[t];
            if (s != cur) { atomicAdd(&enc[cur * 256 + f], a); a = 0.0f; cur = s; }
            a += v;
        }
        atomicAdd(&enc[cur * 256 + f], a);
    }
}

// ---------------- predictor (tiny, fp32) ----------------
__global__ __launch_bounds__(256) void pred_kernel(
    const float* __restrict__ enc,
    const float* __restrict__ P1, const float* __restrict__ pb1,
    const float* __restrict__ P2, const float* __restrict__ pb2,
    const float* __restrict__ P3, const float* __restrict__ pb3,
    float* __restrict__ out) {
    __shared__ float se[256];
    __shared__ float sp[512];
    __shared__ float red[256];
    const int tid = threadIdx.x, b = blockIdx.x;
    se[tid] = enc[b * 256 + tid];
    __syncthreads();
    float a0 = pb1[tid], a1 = pb1[tid + 256];
    for (int k = 0; k < 256; ++k) {
        float e = se[k];
        a0 = fmaf(e, P1[k * 512 + tid], a0);
        a1 = fmaf(e, P1[k * 512 + tid + 256], a1);
    }
    sp[tid] = tanhf(a0);
    sp[tid + 256] = tanhf(a1);
    __syncthreads();
    a0 = pb2[tid]; a1 = pb2[tid + 256];
    for (int k = 0; k < 512; ++k) {
        float p = sp[k];
        a0 = fmaf(p, P2[k * 512 + tid], a0);
        a1 = fmaf(p, P2[k * 512 + tid + 256], a1);
    }
    __syncthreads();
    sp[tid] = tanhf(a0);
    sp[tid + 256] = tanhf(a1);
    __syncthreads();
    int j = tid & 31, part = tid >> 5;
    float s = 0.0f;
    for (int k = part * 64; k < part * 64 + 64; ++k)
        s = fmaf(sp[k], P3[k * 32 + j], s);
    red[tid] = s;
    __syncthreads();
    if (tid < 128) red[tid] += red[tid + 128];
    __syncthreads();
    if (tid < 64) red[tid] += red[tid + 64];
    __syncthreads();
    if (tid < 32) out[b * 32 + tid] = red[tid] + red[tid + 32] + pb3[tid];
}

extern "C" void kernel_launch(void* const* d_in, const int* in_sizes, int n_in,
                              void* d_out, int out_size, void* d_ws, size_t ws_size,
                              hipStream_t stream) {
    const float* words = (const float*)d_in[0];
    const int* seg_ids = (const int*)d_in[1];
    const float* W1 = (const float*)d_in[2];
    const float* b1 = (const float*)d_in[3];
    const float* W2 = (const float*)d_in[4];
    const float* b2 = (const float*)d_in[5];
    const float* W3 = (const float*)d_in[6];
    const float* b3 = (const float*)d_in[7];
    const float* P1 = (const float*)d_in[8];
    const float* pb1 = (const float*)d_in[9];
    const float* P2 = (const float*)d_in[10];
    const float* pb2 = (const float*)d_in[11];
    const float* P3 = (const float*)d_in[12];
    const float* pb3 = (const float*)d_in[13];
    float* out = (float*)d_out;

    char* ws = (char*)d_ws;
    _Float16* W1T = (_Float16*)(ws);            // 512*256*2 = 256KB
    _Float16* W2T = (_Float16*)(ws + 262144);   // 512*512*2 = 512KB
    _Float16* W3T = (_Float16*)(ws + 786432);   // 256*512*2 = 256KB
    float* enc = (float*)(ws + 1048576);        // 128*256*4 = 128KB

    hipMemsetAsync(enc, 0, 128 * 256 * 4, stream);
    wt_kernel<<<524288 / 256, 256, 0, stream>>>(W1, W2, W3, W1T, W2T, W3T);
    encoder_kernel<<<2048, 512, 0, stream>>>(words, seg_ids, W1T, W2T, W3T,
                                             b1, b2, b3, enc);
    pred_kernel<<<128, 256, 0, stream>>>(enc, P1, pb1, P2, pb2, P3, pb3, out);
}

// Round 10
// 290.956 us; speedup vs baseline: 1.4499x; 1.0484x over previous
//
#include <hip/hip_runtime.h>
#include <hip/hip_bf16.h>
#include <hip/hip_fp16.h>

// DeepSetPred: encoder MLP (MFMA fp16) -> segment sum -> predictor MLP (fp32)
// T=131072, E=256, H=512, C=256, O=32, NSEG=128
// R10 = R9 layout/dataflow unchanged; ONLY the K-step sync changes (T4):
//   R9:  stage(s+1); compute(s); __syncthreads()  [vmcnt(0) drains s+1's tile
//        before anyone advances -> fully serial: ~585cy L2 + 512cy MFMA + lat]
//   R10: stage(s+1); s_waitcnt vmcnt(4); s_barrier; compute(s); s_barrier
//        counted gate keeps tile s+1 in flight under compute(s) (m201/T4).
// Correctness: wave passes gate => ITS tile-s loads landed; barrier => ALL
// waves' landed (each passed its own gate). Barrier2 => all ds_reads of tile s
// retired chip-wide before step s+1 overwrites buffer s&1.

typedef _Float16 half8v __attribute__((ext_vector_type(8)));
typedef _Float16 half4v __attribute__((ext_vector_type(4)));
typedef float f32x4 __attribute__((ext_vector_type(4)));
typedef float f32x16 __attribute__((ext_vector_type(16)));

#define TANH_SCALE 2.8853900817779268f  // 2*log2(e)
#define A_STR 1032                      // act row stride bytes (2-way-free, b64)
#define E_STRF 65                       // encT row stride (floats)
#define WTILE 32768                     // one W buffer: 256 rows x 128B

__device__ __forceinline__ void gload_lds16(const void* g, void* l) {
    __builtin_amdgcn_global_load_lds(
        (const __attribute__((address_space(1))) void*)g,
        (__attribute__((address_space(3))) void*)l, 16, 0, 0);
}

// ---------------- weight transpose + fp16 cast (+tanh prescale) --------------
__global__ void wt_kernel(const float* __restrict__ W1, const float* __restrict__ W2,
                          const float* __restrict__ W3,
                          _Float16* __restrict__ W1T, _Float16* __restrict__ W2T,
                          _Float16* __restrict__ W3T) {
    int idx = blockIdx.x * 256 + threadIdx.x;
    if (idx < 131072) {                       // W1 [256][512] -> W1T [512][256], scaled
        int n = idx >> 8, k = idx & 255;
        W1T[idx] = (_Float16)(W1[k * 512 + n] * TANH_SCALE);
    } else if (idx < 393216) {                // W2 [512][512] -> W2T [512][512], scaled
        int j = idx - 131072, n = j >> 9, k = j & 511;
        W2T[j] = (_Float16)(W2[k * 512 + n] * TANH_SCALE);
    } else if (idx < 524288) {                // W3 [512][256] -> W3T [256][512]
        int j = idx - 393216, n = j >> 9, k = j & 511;
        W3T[j] = (_Float16)W3[k * 256 + n];
    }
}

// B fragment from act LDS: two b64 reads (conflict-free at A_STR)
__device__ __forceinline__ half8v read_b(const char* p, int off) {
    uint2 lo = *(const uint2*)(p + off);
    uint2 hi = *(const uint2*)(p + off + 8);
    uint4 w;
    w.x = lo.x; w.y = lo.y; w.z = hi.x; w.w = hi.y;
    return __builtin_bit_cast(half8v, w);
}

__global__ __launch_bounds__(512, 2) void encoder_kernel(
    const float* __restrict__ words, const int* __restrict__ seg_ids,
    const _Float16* __restrict__ W1T, const _Float16* __restrict__ W2T,
    const _Float16* __restrict__ W3T,
    const float* __restrict__ b1, const float* __restrict__ b2,
    const float* __restrict__ b3, float* __restrict__ enc) {
    __shared__ __align__(16) char wbuf[2 * WTILE];  // 64KB: dbuf W tiles [256][128B]
    __shared__ __align__(16) char act[66048];       // 64 x 1032B
    __shared__ __align__(16) float sbias[1280];     // s*b1(512) s*b2(512) b3(256)
    __shared__ int sseg[64];

    const int tid = threadIdx.x;
    const int lane = tid & 63;
    const int wave = tid >> 6;
    const int tok0 = blockIdx.x * 64;

    const int r2 = lane & 31;
    const int hi = lane >> 5;
    const int r7 = (r2 & 7) << 4;

    // ---- staging: W tile LDS slot (row, lslot) <- global k-slot (lslot^(row&7))
    auto stage_w = [&](int buf, const _Float16* Wsrc, int k0, int K) {
        char* dst = wbuf + buf * WTILE;
        #pragma unroll
        for (int it = 0; it < 4; ++it) {
            int c = wave * 4 + it;                       // 1KB chunk = 8 rows
            int row = c * 8 + (lane >> 3);
            int gslot = (lane & 7) ^ (row & 7);
            const _Float16* gp = Wsrc + (size_t)row * K + k0 + gslot * 8;
            gload_lds16(gp, dst + c * 1024);
        }
    };

    auto init_bias = [&](f32x16 acc[2], const float* base) {
        #pragma unroll
        for (int q = 0; q < 4; ++q) {
            f32x4 bv = *(const f32x4*)(base + hi * 4 + q * 8);
            #pragma unroll
            for (int j = 0; j < 4; ++j) {
                acc[0][q * 4 + j] = bv[j];
                acc[1][q * 4 + j] = bv[j];
            }
        }
    };

    const char* actb_base = act + r2 * A_STR + hi * 16;
    // one K-step (64 k): 4 x (A b128 + 2 B reads + 2 MFMA)
    auto compute = [&](f32x16 acc[2], int buf, int kstep) {
        const char* wrow = wbuf + buf * WTILE + (wave * 32 + r2) * 128;
        const char* actb = actb_base + kstep * 128;
        #pragma unroll
        for (int s = 0; s < 4; ++s) {
            half8v A = *(const half8v*)(wrow + ((((s * 2 + hi) << 4)) ^ r7));
            half8v B0 = read_b(actb, s * 32);
            half8v B1 = read_b(actb, 32 * A_STR + s * 32);
            acc[0] = __builtin_amdgcn_mfma_f32_32x32x16_f16(A, B0, acc[0], 0, 0, 0);
            acc[1] = __builtin_amdgcn_mfma_f32_32x32x16_f16(A, B1, acc[1], 0, 0, 0);
        }
    };

    // tanh -> fp16, in-place into act [t][f]
    auto store_h = [&](const f32x16 acc[2], int fbase) {
        #pragma unroll
        for (int nt = 0; nt < 2; ++nt) {
            int t = nt * 32 + r2;
            #pragma unroll
            for (int q = 0; q < 4; ++q) {
                int f0 = fbase + hi * 4 + q * 8;
                half4v hv;
                #pragma unroll
                for (int j = 0; j < 4; ++j) {
                    float e = __builtin_amdgcn_exp2f(acc[nt][q * 4 + j]);
                    float rr = __builtin_amdgcn_rcpf(e + 1.0f);
                    hv[j] = (_Float16)fmaf(-2.0f, rr, 1.0f);
                }
                *(half4v*)(act + t * A_STR + f0 * 2) = hv;
            }
        }
    };

    // pipelined K-step: counted vmcnt gate + two raw barriers (T4)
    auto kstep_sync = [&](bool staged) {
        if (staged) asm volatile("s_waitcnt vmcnt(4)" ::: "memory");
        else        asm volatile("s_waitcnt vmcnt(0)" ::: "memory");
        __builtin_amdgcn_s_barrier();
        __builtin_amdgcn_sched_barrier(0);
    };

    // ---- prologue ----
    sbias[tid] = b1[tid] * TANH_SCALE;
    sbias[512 + tid] = b2[tid] * TANH_SCALE;
    if (tid < 256) sbias[1024 + tid] = b3[tid];
    if (tid < 64) sseg[tid] = seg_ids[tok0 + tid];

    {   // stage words tile -> fp16 act rows (coalesced fp32 reads)
        const float* wsrc = words + (size_t)tok0 * 256;
        #pragma unroll
        for (int it = 0; it < 8; ++it) {
            int i = it * 512 + tid;
            float4 v = ((const float4*)wsrc)[i];
            int t = i >> 6;
            int col = i & 63;
            half4v hv = { (_Float16)v.x, (_Float16)v.y, (_Float16)v.z, (_Float16)v.w };
            *(half4v*)(act + t * A_STR + col * 8) = hv;
        }
    }
    stage_w(0, W1T, 0, 256);
    __syncthreads();

    int buf = 0;
    f32x16 accA[2], accB[2];

    // ================= layer 1: K=256, out 512 (2 passes) =================
    init_bias(accA, sbias + wave * 32);
    init_bias(accB, sbias + 256 + wave * 32);
    #pragma unroll
    for (int s = 0; s < 4; ++s) {           // pass 0
        if (s < 3) stage_w(buf ^ 1, W1T, (s + 1) * 64, 256);
        else       stage_w(buf ^ 1, W1T + 256 * 256, 0, 256);
        kstep_sync(true);
        compute(accA, buf, s);
        __builtin_amdgcn_sched_barrier(0);
        __builtin_amdgcn_s_barrier();
        buf ^= 1;
    }
    #pragma unroll
    for (int s = 0; s < 4; ++s) {           // pass 1
        if (s < 3) stage_w(buf ^ 1, W1T + 256 * 256, (s + 1) * 64, 256);
        else       stage_w(buf ^ 1, W2T, 0, 512);   // prefetch L2 tile 0
        kstep_sync(true);
        compute(accB, buf, s);
        __builtin_amdgcn_sched_barrier(0);
        __builtin_amdgcn_s_barrier();
        buf ^= 1;
    }
    store_h(accA, wave * 32);
    store_h(accB, 256 + wave * 32);
    __syncthreads();

    // ================= layer 2: K=512, out 512 (2 passes) =================
    init_bias(accA, sbias + 512 + wave * 32);
    init_bias(accB, sbias + 768 + wave * 32);
    #pragma unroll
    for (int s = 0; s < 8; ++s) {           // pass 0
        if (s < 7) stage_w(buf ^ 1, W2T, (s + 1) * 64, 512);
        else       stage_w(buf ^ 1, W2T + 256 * 512, 0, 512);
        kstep_sync(true);
        compute(accA, buf, s);
        __builtin_amdgcn_sched_barrier(0);
        __builtin_amdgcn_s_barrier();
        buf ^= 1;
    }
    #pragma unroll
    for (int s = 0; s < 8; ++s) {           // pass 1
        if (s < 7) stage_w(buf ^ 1, W2T + 256 * 512, (s + 1) * 64, 512);
        else       stage_w(buf ^ 1, W3T, 0, 512);   // prefetch L3 tile 0
        kstep_sync(true);
        compute(accB, buf, s);
        __builtin_amdgcn_sched_barrier(0);
        __builtin_amdgcn_s_barrier();
        buf ^= 1;
    }
    store_h(accA, wave * 32);
    store_h(accB, 256 + wave * 32);
    __syncthreads();

    // ================= layer 3: K=512, out 256 (1 pass, f32, no tanh) =====
    init_bias(accA, sbias + 1024 + wave * 32);
    #pragma unroll
    for (int s = 0; s < 8; ++s) {
        bool st = (s < 7);
        if (st) stage_w(buf ^ 1, W3T, (s + 1) * 64, 512);
        kstep_sync(st);
        compute(accA, buf, s);
        __builtin_amdgcn_sched_barrier(0);
        __builtin_amdgcn_s_barrier();
        buf ^= 1;
    }
    {   // encT [256 f][65 floats] into act buffer (reads done)
        float* encT = (float*)act;
        #pragma unroll
        for (int nt = 0; nt < 2; ++nt) {
            int t = nt * 32 + r2;
            #pragma unroll
            for (int q = 0; q < 4; ++q) {
                int f0 = wave * 32 + hi * 4 + q * 8;
                #pragma unroll
                for (int j = 0; j < 4; ++j)
                    encT[(f0 + j) * E_STRF + t] = accA[nt][q * 4 + j];
            }
        }
    }
    __syncthreads();

    // segment reduction: sorted seg_ids -> running sum, atomic on boundary
    {
        int f = tid & 255;
        int hh = tid >> 8;
        int t0 = hh * 32;
        const float* encT = (const float*)act;
        float a = 0.0f;
        int cur = sseg[t0];
        for (int i = 0; i < 32; ++i) {
            int t = t0 + i;
            float v = encT[f * E_STRF + t];
            int s = sseg[t];
            if (s != cur) { atomicAdd(&enc[cur * 256 + f], a); a = 0.0f; cur = s; }
            a += v;
        }
        atomicAdd(&enc[cur * 256 + f], a);
    }
}

// ---------------- predictor (tiny, fp32) ----------------
__global__ __launch_bounds__(256) void pred_kernel(
    const float* __restrict__ enc,
    const float* __restrict__ P1, const float* __restrict__ pb1,
    const float* __restrict__ P2, const float* __restrict__ pb2,
    const float* __restrict__ P3, const float* __restrict__ pb3,
    float* __restrict__ out) {
    __shared__ float se[256];
    __shared__ float sp[512];
    __shared__ float red[256];
    const int tid = threadIdx.x, b = blockIdx.x;
    se[tid] = enc[b * 256 + tid];
    __syncthreads();
    float a0 = pb1[tid], a1 = pb1[tid + 256];
    for (int k = 0; k < 256; ++k) {
        float e = se[k];
        a0 = fmaf(e, P1[k * 512 + tid], a0);
        a1 = fmaf(e, P1[k * 512 + tid + 256], a1);
    }
    sp[tid] = tanhf(a0);
    sp[tid + 256] = tanhf(a1);
    __syncthreads();
    a0 = pb2[tid]; a1 = pb2[tid + 256];
    for (int k = 0; k < 512; ++k) {
        float p = sp[k];
        a0 = fmaf(p, P2[k * 512 + tid], a0);
        a1 = fmaf(p, P2[k * 512 + tid + 256], a1);
    }
    __syncthreads();
    sp[tid] = tanhf(a0);
    sp[tid + 256] = tanhf(a1);
    __syncthreads();
    int j = tid & 31, part = tid >> 5;
    float s = 0.0f;
    for (int k = part * 64; k < part * 64 + 64; ++k)
        s = fmaf(sp[k], P3[k * 32 + j], s);
    red[tid] = s;
    __syncthreads();
    if (tid < 128) red[tid] += red[tid + 128];
    __syncthreads();
    if (tid < 64) red[tid] += red[tid + 64];
    __syncthreads();
    if (tid < 32) out[b * 32 + tid] = red[tid] + red[tid + 32] + pb3[tid];
}

extern "C" void kernel_launch(void* const* d_in, const int* in_sizes, int n_in,
                              void* d_out, int out_size, void* d_ws, size_t ws_size,
                              hipStream_t stream) {
    const float* words = (const float*)d_in[0];
    const int* seg_ids = (const int*)d_in[1];
    const float* W1 = (const float*)d_in[2];
    const float* b1 = (const float*)d_in[3];
    const float* W2 = (const float*)d_in[4];
    const float* b2 = (const float*)d_in[5];
    const float* W3 = (const float*)d_in[6];
    const float* b3 = (const float*)d_in[7];
    const float* P1 = (const float*)d_in[8];
    const float* pb1 = (const float*)d_in[9];
    const float* P2 = (const float*)d_in[10];
    const float* pb2 = (const float*)d_in[11];
    const float* P3 = (const float*)d_in[12];
    const float* pb3 = (const float*)d_in[13];
    float* out = (float*)d_out;

    char* ws = (char*)d_ws;
    _Float16* W1T = (_Float16*)(ws);            // 512*256*2 = 256KB
    _Float16* W2T = (_Float16*)(ws + 262144);   // 512*512*2 = 512KB
    _Float16* W3T = (_Float16*)(ws + 786432);   // 256*512*2 = 256KB
    float* enc = (float*)(ws + 1048576);        // 128*256*4 = 128KB

    hipMemsetAsync(enc, 0, 128 * 256 * 4, stream);
    wt_kernel<<<524288 / 256, 256, 0, stream>>>(W1, W2, W3, W1T, W2T, W3T);
    encoder_kernel<<<2048, 512, 0, stream>>>(words, seg_ids, W1T, W2T, W3T,
                                             b1, b2, b3, enc);
    pred_kernel<<<128, 256, 0, stream>>>(enc, P1, pb1, P2, pb2, P3, pb3, out);
}